// Round 10
// baseline (258.677 us; speedup 1.0000x reference)
//
#include <hip/hip_runtime.h>

#define N_NODES 50000
#define N_EDGES 800000
#define D 64
#define BIN_NODES 16          // nodes per bin (tgt>>4)
#define BINS 3125             // 50000 / 16 exactly
#define BIN_CAP 448           // edges/bin: mean 256, sigma 16 -> +12 sigma
#define NODE_CAP 64           // per-node bucket: deg ~ Poisson(16)
#define BROW 72               // LDS bucket row stride (u16): 144 B, 8B-aligned,
                              // group base banks 0/4/8/12 within a wave
#define GEMV_BLOCKS 3125      // tmp = merge@W_tr^T + b_tr (4 rows/wave, stride)
#define BINNING_BLOCKS 3125   // 800000 / 256
#define CVT_BLOCKS 3125       // 50000*64/4 float4 / 256
#define K1_BLOCKS (GEMV_BLOCKS + BINNING_BLOCKS + CVT_BLOCKS)

// round-to-nearest-even fp32 -> bf16 (low 16 bits)
__device__ __forceinline__ unsigned int f2bf(float f) {
    unsigned int u = __builtin_bit_cast(unsigned int, f);
    return (u + 0x7fffu + ((u >> 16) & 1u)) >> 16;
}
__device__ __forceinline__ float bflo(unsigned int v) {
    return __builtin_bit_cast(float, v << 16);
}
__device__ __forceinline__ float bfhi(unsigned int v) {
    return __builtin_bit_cast(float, v & 0xffff0000u);
}

// ---------------------------------------------------------------------------
// K1: three independent roles in one dispatch (longest first).
//  [0, GEMV):        tmp = merge @ W_tr^T + b_tr      (graph-independent)
//  [GEMV, +BINNING): coarse-bin the edges: pairs[bin] += (tlocal<<16)|src.
//    3125 bins -> ~400 KB of hot append frontiers; lines fill fully before
//    eviction (kills round-8/9's 47-51 MB bucket writeback churn).
//  [.., +CVT):       data16 = bf16(data), RNE, coalesced.
// ---------------------------------------------------------------------------
__global__ __launch_bounds__(256) void k1_kernel(
        const float* __restrict__ data,
        const float* __restrict__ merge,
        const int* __restrict__ src, const int* __restrict__ tgt,
        const float* __restrict__ W_tr, const float* __restrict__ b_tr,
        unsigned short* __restrict__ data16,
        int* __restrict__ binCur, unsigned int* __restrict__ pairs,
        float* __restrict__ tmp) {
    int b = blockIdx.x;
    int tid = threadIdx.x;
    if (b < GEMV_BLOCKS) {
        int lane = tid & 63;
        int slot = tid >> 6;
        float4 Wr[16];
        const float4* wrow = (const float4*)(W_tr + (size_t)lane * D);
#pragma unroll
        for (int i = 0; i < 16; i++) Wr[i] = wrow[i];
        float bias = b_tr[lane];

        const int stride = GEMV_BLOCKS * 4;
        int r = b * 4 + slot;
        float rv = merge[(size_t)r * D + lane];
        while (r < N_NODES) {
            int rn = r + stride;
            float rv_next = 0.f;
            if (rn < N_NODES) rv_next = merge[(size_t)rn * D + lane];
            float a0 = 0.f, a1 = 0.f, a2 = 0.f, a3 = 0.f;
#pragma unroll
            for (int i = 0; i < 16; i++) {
                a0 += __shfl(rv, 4 * i)     * Wr[i].x;
                a1 += __shfl(rv, 4 * i + 1) * Wr[i].y;
                a2 += __shfl(rv, 4 * i + 2) * Wr[i].z;
                a3 += __shfl(rv, 4 * i + 3) * Wr[i].w;
            }
            tmp[(size_t)r * D + lane] = ((a0 + a1) + (a2 + a3)) + bias;
            rv = rv_next;
            r = rn;
        }
    } else if (b < GEMV_BLOCKS + BINNING_BLOCKS) {
        int e = (b - GEMV_BLOCKS) * 256 + tid;
        int t = tgt[e];
        int bin = t >> 4;
        int pos = atomicAdd(&binCur[bin], 1);
        if (pos < BIN_CAP)
            pairs[(size_t)bin * BIN_CAP + pos] =
                (unsigned int)src[e] | ((unsigned int)(t & 15) << 16);
    } else {
        int i = (b - GEMV_BLOCKS - BINNING_BLOCKS) * 256 + tid;  // float4 idx
        float4 d = ((const float4*)data)[i];
        uint2 v;
        v.x = f2bf(d.x) | (f2bf(d.y) << 16);
        v.y = f2bf(d.z) | (f2bf(d.w) << 16);
        ((uint2*)data16)[i] = v;
    }
}

// ---------------------------------------------------------------------------
// K2: one block per bin (16 nodes). Phases:
//  1. scatter bin's ~256 pairs into LDS per-node buckets (LDS atomics;
//     cursor counts full degree).
//  2. 16-lane group per node: gather bf16 rows from data16 (indices read
//     from LDS, broadcast; 4 acc chains for MLP), h = own - mean, to LDS.
//  3. fused GEMV: out = relu(h @ W_lin^T + tmp). W_lin in 64 VGPRs; h row
//     read same-addr across wave (LDS broadcast). No h global round-trip.
// ---------------------------------------------------------------------------
__global__ __launch_bounds__(256) void k2_kernel(
        const float* __restrict__ data,
        const unsigned short* __restrict__ data16,
        const int* __restrict__ binCur,
        const unsigned int* __restrict__ pairs,
        const float* __restrict__ tmp,
        const float* __restrict__ W_lin,
        float* __restrict__ out) {
    __shared__ unsigned short lbkt[BIN_NODES * BROW];   // 2.25 KB
    __shared__ int lcur[BIN_NODES];
    __shared__ float hbuf[BIN_NODES * D];               // 4 KB

    int tid = threadIdx.x;
    int lane = tid & 63;

    float4 Wr[16];                    // W_lin row for output column `lane`
    const float4* wrow = (const float4*)(W_lin + (size_t)lane * D);
#pragma unroll
    for (int i = 0; i < 16; i++) Wr[i] = wrow[i];

    int bin = blockIdx.x;
    int base = bin * BIN_NODES;

    if (tid < BIN_NODES) lcur[tid] = 0;
    __syncthreads();

    int cnt = binCur[bin];
    if (cnt > BIN_CAP) cnt = BIN_CAP;
    for (int i = tid; i < cnt; i += 256) {
        unsigned int p = pairs[(size_t)bin * BIN_CAP + i];
        int tl = p >> 16;
        int pos = atomicAdd(&lcur[tl], 1);
        if (pos < NODE_CAP) lbkt[tl * BROW + pos] = (unsigned short)(p & 0xffffu);
    }
    __syncthreads();

    // ---- gather phase: group gid = tid>>4 owns node base+gid ----
    int gid = tid >> 4;
    int m = tid & 15;                  // owns cols 4m..4m+3
    int n = base + gid;
    int dg = lcur[gid];                // full degree
    int dgc = dg < NODE_CAP ? dg : NODE_CAP;
    float4 own = ((const float4*)(data + (size_t)n * D))[m];

    float4 a0 = {0,0,0,0}, a1 = {0,0,0,0}, a2 = {0,0,0,0}, a3 = {0,0,0,0};
    const uint2* brow = (const uint2*)(lbkt + gid * BROW);
    int nbJ = (dgc + 3) >> 2;
    for (int jb = 0; jb < nbJ; jb++) {
        uint2 iw = brow[jb];           // 4 u16 indices, LDS broadcast in group
        int j0 = jb * 4;
        if (j0 < dgc) {
            uint2 v = ((const uint2*)(data16 + (size_t)(iw.x & 0xffffu) * D))[m];
            a0.x += bflo(v.x); a0.y += bfhi(v.x);
            a0.z += bflo(v.y); a0.w += bfhi(v.y);
        }
        if (j0 + 1 < dgc) {
            uint2 v = ((const uint2*)(data16 + (size_t)(iw.x >> 16) * D))[m];
            a1.x += bflo(v.x); a1.y += bfhi(v.x);
            a1.z += bflo(v.y); a1.w += bfhi(v.y);
        }
        if (j0 + 2 < dgc) {
            uint2 v = ((const uint2*)(data16 + (size_t)(iw.y & 0xffffu) * D))[m];
            a2.x += bflo(v.x); a2.y += bfhi(v.x);
            a2.z += bflo(v.y); a2.w += bfhi(v.y);
        }
        if (j0 + 3 < dgc) {
            uint2 v = ((const uint2*)(data16 + (size_t)(iw.y >> 16) * D))[m];
            a3.x += bflo(v.x); a3.y += bfhi(v.x);
            a3.z += bflo(v.y); a3.w += bfhi(v.y);
        }
    }
    float4 s;
    s.x = (a0.x + a1.x) + (a2.x + a3.x);
    s.y = (a0.y + a1.y) + (a2.y + a3.y);
    s.z = (a0.z + a1.z) + (a2.z + a3.z);
    s.w = (a0.w + a1.w) + (a2.w + a3.w);

    float inv  = dg > 0 ? 1.0f / (float)dg : 0.0f;
    float mask = dg > 0 ? 1.0f : 0.0f;
    float4 hv;
    hv.x = (own.x - s.x * inv) * mask;
    hv.y = (own.y - s.y * inv) * mask;
    hv.z = (own.z - s.z * inv) * mask;
    hv.w = (own.w - s.w * inv) * mask;
    ((float4*)(hbuf + gid * D))[m] = hv;
    __syncthreads();

    // ---- fused GEMV: wave w handles its own 4 nodes (gids 4w..4w+3) ----
    int w = tid >> 6;
#pragma unroll
    for (int tg = 0; tg < 4; tg++) {
        int t = w * 4 + tg;
        const float4* hrow = (const float4*)(hbuf + t * D);
        float acc = 0.f;
#pragma unroll
        for (int i = 0; i < 16; i++) {
            float4 hq = hrow[i];       // same addr across wave -> broadcast
            acc += hq.x * Wr[i].x + hq.y * Wr[i].y
                 + hq.z * Wr[i].z + hq.w * Wr[i].w;
        }
        int nn = base + t;
        float o = acc + tmp[(size_t)nn * D + lane];
        out[(size_t)nn * D + lane] = o > 0.f ? o : 0.f;
    }
}

extern "C" void kernel_launch(void* const* d_in, const int* in_sizes, int n_in,
                              void* d_out, int out_size, void* d_ws, size_t ws_size,
                              hipStream_t stream) {
    const float* data  = (const float*)d_in[0];
    const float* merge = (const float*)d_in[1];
    const int*   src   = (const int*)d_in[2];
    const int*   tgt   = (const int*)d_in[3];
    // d_in[4]=W_lin, d_in[5]=b_lin (cancels in lap), d_in[6]=W_tr, d_in[7]=b_tr
    const float* W_lin = (const float*)d_in[4];
    const float* W_tr  = (const float*)d_in[6];
    const float* b_tr  = (const float*)d_in[7];
    float* out = (float*)d_out;

    // Workspace: binCur [BINS i32] | pairs [BINS*BIN_CAP u32] (5.6 MB)
    //            | data16 [N*D bf16] (6.4 MB) | tmp [N*D f32] (12.8 MB)
    char* ws = (char*)d_ws;
    size_t o = 0;
    int*            binCur = (int*)(ws + o);            o += (size_t)BINS * 4;
    unsigned int*   pairs  = (unsigned int*)(ws + o);   o += (size_t)BINS * BIN_CAP * 4;
    unsigned short* data16 = (unsigned short*)(ws + o); o += (size_t)N_NODES * D * 2;
    float*          tmp    = (float*)(ws + o);          o += (size_t)N_NODES * D * 4;

    hipMemsetAsync(binCur, 0, (size_t)BINS * 4, stream);

    k1_kernel<<<K1_BLOCKS, 256, 0, stream>>>(
        data, merge, src, tgt, W_tr, b_tr, data16, binCur, pairs, tmp);

    k2_kernel<<<BINS, 256, 0, stream>>>(
        data, data16, binCur, pairs, tmp, W_lin, out);
}

// Round 11
// 206.529 us; speedup vs baseline: 1.2525x; 1.2525x over previous
//
#include <hip/hip_runtime.h>

#define N_NODES 50000
#define N_EDGES 800000
#define D 64
#define COARSE 49            // coarse bins of 1024 nodes (tgt>>10)
#define CCAP 17024           // mean 16384, sigma ~127 -> +5 sigma
#define BINS 3125            // fine bins of 16 nodes (50000/16)
#define BIN_NODES 16
#define NODE_CAP 64          // deg ~ Poisson(16); P(>64) ~ 1e-18
#define BROW 72              // u16 stride per node bucket row: 144 B, 16B-mult
#define KA_BLOCKS 391        // 2048 edges per block (last: 1280)
#define GEMV_BLOCKS 3125
#define CVT_BLOCKS 3125
#define K1_BLOCKS (KA_BLOCKS + GEMV_BLOCKS + CVT_BLOCKS)

__device__ __forceinline__ unsigned int f2bf(float f) {
    unsigned int u = __builtin_bit_cast(unsigned int, f);
    return (u + 0x7fffu + ((u >> 16) & 1u)) >> 16;
}
__device__ __forceinline__ float bflo(unsigned int v) {
    return __builtin_bit_cast(float, v << 16);
}
__device__ __forceinline__ float bfhi(unsigned int v) {
    return __builtin_bit_cast(float, v & 0xffff0000u);
}

// ---------------------------------------------------------------------------
// K1: three independent roles in one dispatch.
//  [0, KA):   coarse binning with BLOCK-PRIVATE clean writes. LDS hist over
//    49 bins, ONE global atomicAdd per (block,bin) to reserve a contiguous
//    run (~42 u32), scatter into the exclusive run. Kills the 12-18x
//    write amplification of per-edge scattered appends (R8-R10 lesson).
//  [KA, +GEMV):  tmp = merge @ W_tr^T + b_tr   (graph-independent)
//  [.., +CVT):   data16 = bf16(data), RNE, coalesced.
// ---------------------------------------------------------------------------
__global__ __launch_bounds__(256) void k1_kernel(
        const float* __restrict__ data,
        const float* __restrict__ merge,
        const int* __restrict__ src, const int* __restrict__ tgt,
        const float* __restrict__ W_tr, const float* __restrict__ b_tr,
        unsigned short* __restrict__ data16,
        int* __restrict__ gCur, unsigned int* __restrict__ gPairs,
        float* __restrict__ tmp) {
    int b = blockIdx.x;
    int tid = threadIdx.x;
    if (b < KA_BLOCKS) {
        __shared__ unsigned int epair[2048];
        __shared__ int hist[COARSE], rbase[COARSE], cur2[COARSE];
        int eb = b * 2048;
        int n = N_EDGES - eb; if (n > 2048) n = 2048;
        if (tid < COARSE) { hist[tid] = 0; cur2[tid] = 0; }
        __syncthreads();
        for (int i = tid; i < n; i += 256) {
            int t = tgt[eb + i];
            unsigned int p = ((unsigned int)t << 16) | (unsigned int)src[eb + i];
            epair[i] = p;
            atomicAdd(&hist[t >> 10], 1);
        }
        __syncthreads();
        if (tid < COARSE && hist[tid] > 0)
            rbase[tid] = atomicAdd(&gCur[tid], hist[tid]);
        __syncthreads();
        for (int i = tid; i < n; i += 256) {
            unsigned int p = epair[i];
            int c = p >> 26;                       // tgt>>10
            int pos = rbase[c] + atomicAdd(&cur2[c], 1);
            if (pos < CCAP) gPairs[(size_t)c * CCAP + pos] = p;
        }
    } else if (b < KA_BLOCKS + GEMV_BLOCKS) {
        int gb = b - KA_BLOCKS;
        int lane = tid & 63;
        int slot = tid >> 6;
        float4 Wr[16];
        const float4* wrow = (const float4*)(W_tr + (size_t)lane * D);
#pragma unroll
        for (int i = 0; i < 16; i++) Wr[i] = wrow[i];
        float bias = b_tr[lane];
        const int stride = GEMV_BLOCKS * 4;
        int r = gb * 4 + slot;
        float rv = merge[(size_t)r * D + lane];
        while (r < N_NODES) {
            int rn = r + stride;
            float rv_next = 0.f;
            if (rn < N_NODES) rv_next = merge[(size_t)rn * D + lane];
            float a0 = 0.f, a1 = 0.f, a2 = 0.f, a3 = 0.f;
#pragma unroll
            for (int i = 0; i < 16; i++) {
                a0 += __shfl(rv, 4 * i)     * Wr[i].x;
                a1 += __shfl(rv, 4 * i + 1) * Wr[i].y;
                a2 += __shfl(rv, 4 * i + 2) * Wr[i].z;
                a3 += __shfl(rv, 4 * i + 3) * Wr[i].w;
            }
            tmp[(size_t)r * D + lane] = ((a0 + a1) + (a2 + a3)) + bias;
            rv = rv_next;
            r = rn;
        }
    } else {
        int i = (b - KA_BLOCKS - GEMV_BLOCKS) * 256 + tid;   // float4 index
        float4 d = ((const float4*)data)[i];
        uint2 v;
        v.x = f2bf(d.x) | (f2bf(d.y) << 16);
        v.y = f2bf(d.z) | (f2bf(d.w) << 16);
        ((uint2*)data16)[i] = v;
    }
}

// ---------------------------------------------------------------------------
// KB: one block per coarse bin. Refine into 64 fine bins (16 nodes each):
// LDS hist -> serial prefix -> exclusive-region scatter. ZERO global atomics;
// writes are ~1 KB contiguous runs. Emits gFineOff/gFineCnt per fine bin.
// ---------------------------------------------------------------------------
__global__ __launch_bounds__(512) void kb_kernel(
        const int* __restrict__ gCur,
        const unsigned int* __restrict__ gPairs,
        unsigned int* __restrict__ gSorted,
        int* __restrict__ gFineOff, int* __restrict__ gFineCnt) {
    __shared__ int hist[64], off[64], cur[64];
    int c = blockIdx.x;
    int tid = threadIdx.x;
    int cnt = gCur[c]; if (cnt > CCAP) cnt = CCAP;
    if (tid < 64) { hist[tid] = 0; cur[tid] = 0; }
    __syncthreads();
    for (int i = tid; i < cnt; i += 512)
        atomicAdd(&hist[(gPairs[(size_t)c * CCAP + i] >> 20) & 63], 1);
    __syncthreads();
    if (tid == 0) {
        int a = 0;
        for (int f = 0; f < 64; f++) { off[f] = a; a += hist[f]; }
    }
    __syncthreads();
    if (tid < 64) {
        int bin = c * 64 + tid;
        if (bin < BINS) {
            gFineOff[bin] = c * CCAP + off[tid];
            gFineCnt[bin] = hist[tid];
        }
    }
    for (int i = tid; i < cnt; i += 512) {
        unsigned int p = gPairs[(size_t)c * CCAP + i];
        int f = (p >> 20) & 63;
        int pos = off[f] + atomicAdd(&cur[f], 1);
        gSorted[(size_t)c * CCAP + pos] = p;
    }
}

// ---------------------------------------------------------------------------
// K2: one block per fine bin (16 nodes).
//  1. contiguous pair read -> LDS per-node buckets (LDS atomics; full degree).
//  2. gather: 8-lane group per (node, parity); lane owns cols 8l..8l+7 and
//     loads uint4 (16 B bf16) -> ONE wave-instruction fetches 8 rows (1 KB),
//     2x fewer VMEM instrs + 32 loads in flight per wave. Indices read from
//     LDS (broadcast, no shfl in divergent loop). 4 chains/group.
//  3. parity halves combined via shfl_xor(8) after reconvergence; h to LDS.
//  4. fused GEMV: out = relu(h @ W_lin^T + tmp). W_lin in 64 VGPRs.
// ---------------------------------------------------------------------------
__global__ __launch_bounds__(256) void k2_kernel(
        const float* __restrict__ data,
        const unsigned short* __restrict__ data16,
        const int* __restrict__ gFineOff, const int* __restrict__ gFineCnt,
        const unsigned int* __restrict__ gSorted,
        const float* __restrict__ tmp,
        const float* __restrict__ W_lin,
        float* __restrict__ out) {
    __shared__ __align__(16) unsigned short lbkt[BIN_NODES * BROW];  // 2.25 KB
    __shared__ int lcur[BIN_NODES];
    __shared__ float hbuf[BIN_NODES * D];                            // 4 KB

    int tid = threadIdx.x;
    int lane = tid & 63;
    int bin = blockIdx.x;
    int nodeBase = bin * BIN_NODES;

    float4 Wr[16];
    const float4* wrow = (const float4*)(W_lin + (size_t)lane * D);
#pragma unroll
    for (int i = 0; i < 16; i++) Wr[i] = wrow[i];

    if (tid < BIN_NODES) lcur[tid] = 0;
    __syncthreads();

    int beg = gFineOff[bin];
    int cnt = gFineCnt[bin];
    for (int i = tid; i < cnt; i += 256) {
        unsigned int p = gSorted[(size_t)beg + i];
        int tl = (p >> 16) & 15;
        int pos = atomicAdd(&lcur[tl], 1);
        if (pos < NODE_CAP) lbkt[tl * BROW + pos] = (unsigned short)(p & 0xffffu);
    }
    __syncthreads();

    // ---- gather: group G = tid>>3 -> node G>>1, parity G&1; lane ln=tid&7 ----
    int G = tid >> 3;
    int ln = tid & 7;
    int node = G >> 1;
    int par = G & 1;
    int n = nodeBase + node;
    int dg = lcur[node];
    int dgc = dg < NODE_CAP ? dg : NODE_CAP;

    const float4* orow = (const float4*)(data + (size_t)n * D + 8 * ln);
    float4 o0 = orow[0], o1 = orow[1];

    float a0[8] = {0,0,0,0,0,0,0,0}, a1[8] = {0,0,0,0,0,0,0,0};
    float a2[8] = {0,0,0,0,0,0,0,0}, a3[8] = {0,0,0,0,0,0,0,0};
    // entries: e = it*8 + par*4 + ci  (ci = chain)
    const uint2* idxp = (const uint2*)(lbkt + node * BROW + par * 4);
    int nIt = (dgc + 7) >> 3;
    for (int it = 0; it < nIt; it++) {
        uint2 iw = idxp[it * 2];            // 4 u16 indices, LDS broadcast
        int e0 = it * 8 + par * 4;
        unsigned int i0 = iw.x & 0xffffu, i1 = iw.x >> 16;
        unsigned int i2 = iw.y & 0xffffu, i3 = iw.y >> 16;
        if (e0 < dgc) {
            uint4 v = *(const uint4*)(data16 + (size_t)i0 * D + 8 * ln);
            a0[0] += bflo(v.x); a0[1] += bfhi(v.x); a0[2] += bflo(v.y); a0[3] += bfhi(v.y);
            a0[4] += bflo(v.z); a0[5] += bfhi(v.z); a0[6] += bflo(v.w); a0[7] += bfhi(v.w);
        }
        if (e0 + 1 < dgc) {
            uint4 v = *(const uint4*)(data16 + (size_t)i1 * D + 8 * ln);
            a1[0] += bflo(v.x); a1[1] += bfhi(v.x); a1[2] += bflo(v.y); a1[3] += bfhi(v.y);
            a1[4] += bflo(v.z); a1[5] += bfhi(v.z); a1[6] += bflo(v.w); a1[7] += bfhi(v.w);
        }
        if (e0 + 2 < dgc) {
            uint4 v = *(const uint4*)(data16 + (size_t)i2 * D + 8 * ln);
            a2[0] += bflo(v.x); a2[1] += bfhi(v.x); a2[2] += bflo(v.y); a2[3] += bfhi(v.y);
            a2[4] += bflo(v.z); a2[5] += bfhi(v.z); a2[6] += bflo(v.w); a2[7] += bfhi(v.w);
        }
        if (e0 + 3 < dgc) {
            uint4 v = *(const uint4*)(data16 + (size_t)i3 * D + 8 * ln);
            a3[0] += bflo(v.x); a3[1] += bfhi(v.x); a3[2] += bflo(v.y); a3[3] += bfhi(v.y);
            a3[4] += bflo(v.z); a3[5] += bfhi(v.z); a3[6] += bflo(v.w); a3[7] += bfhi(v.w);
        }
    }
    float s[8];
#pragma unroll
    for (int k = 0; k < 8; k++) s[k] = (a0[k] + a1[k]) + (a2[k] + a3[k]);
#pragma unroll
    for (int k = 0; k < 8; k++) s[k] += __shfl_xor(s[k], 8);  // combine parities

    if (par == 0) {
        float inv  = dg > 0 ? 1.0f / (float)dg : 0.0f;
        float msk  = dg > 0 ? 1.0f : 0.0f;
        float4 h0, h1;
        h0.x = (o0.x - s[0] * inv) * msk; h0.y = (o0.y - s[1] * inv) * msk;
        h0.z = (o0.z - s[2] * inv) * msk; h0.w = (o0.w - s[3] * inv) * msk;
        h1.x = (o1.x - s[4] * inv) * msk; h1.y = (o1.y - s[5] * inv) * msk;
        h1.z = (o1.z - s[6] * inv) * msk; h1.w = (o1.w - s[7] * inv) * msk;
        float4* hp = (float4*)(hbuf + node * D + 8 * ln);
        hp[0] = h0; hp[1] = h1;
    }
    __syncthreads();

    // ---- fused GEMV: wave w -> nodes 4w..4w+3 ----
    int w = tid >> 6;
#pragma unroll
    for (int tg = 0; tg < 4; tg++) {
        int t = w * 4 + tg;
        const float4* hrow = (const float4*)(hbuf + t * D);
        float acc = 0.f;
#pragma unroll
        for (int i = 0; i < 16; i++) {
            float4 hq = hrow[i];           // same addr across wave -> broadcast
            acc += hq.x * Wr[i].x + hq.y * Wr[i].y
                 + hq.z * Wr[i].z + hq.w * Wr[i].w;
        }
        int nn = nodeBase + t;
        float o = acc + tmp[(size_t)nn * D + lane];
        out[(size_t)nn * D + lane] = o > 0.f ? o : 0.f;
    }
}

extern "C" void kernel_launch(void* const* d_in, const int* in_sizes, int n_in,
                              void* d_out, int out_size, void* d_ws, size_t ws_size,
                              hipStream_t stream) {
    const float* data  = (const float*)d_in[0];
    const float* merge = (const float*)d_in[1];
    const int*   src   = (const int*)d_in[2];
    const int*   tgt   = (const int*)d_in[3];
    // d_in[4]=W_lin, d_in[5]=b_lin (cancels in lap), d_in[6]=W_tr, d_in[7]=b_tr
    const float* W_lin = (const float*)d_in[4];
    const float* W_tr  = (const float*)d_in[6];
    const float* b_tr  = (const float*)d_in[7];
    float* out = (float*)d_out;

    // Workspace: gCur[49] | gPairs[49*CCAP u32] | gSorted[49*CCAP u32]
    //            | gFineOff[3125] | gFineCnt[3125] | data16[N*D bf16]
    //            | tmp[N*D f32]                      (~26 MB)
    char* ws = (char*)d_ws;
    size_t o = 0;
    int*            gCur     = (int*)(ws + o);            o += 64 * 4;
    unsigned int*   gPairs   = (unsigned int*)(ws + o);   o += (size_t)COARSE * CCAP * 4;
    unsigned int*   gSorted  = (unsigned int*)(ws + o);   o += (size_t)COARSE * CCAP * 4;
    int*            gFineOff = (int*)(ws + o);            o += (size_t)BINS * 4;
    int*            gFineCnt = (int*)(ws + o);            o += (size_t)BINS * 4;
    unsigned short* data16   = (unsigned short*)(ws + o); o += (size_t)N_NODES * D * 2;
    float*          tmp      = (float*)(ws + o);          o += (size_t)N_NODES * D * 4;

    hipMemsetAsync(gCur, 0, 64 * 4, stream);

    k1_kernel<<<K1_BLOCKS, 256, 0, stream>>>(
        data, merge, src, tgt, W_tr, b_tr, data16, gCur, gPairs, tmp);

    kb_kernel<<<COARSE, 512, 0, stream>>>(
        gCur, gPairs, gSorted, gFineOff, gFineCnt);

    k2_kernel<<<BINS, 256, 0, stream>>>(
        data, data16, gFineOff, gFineCnt, gSorted, tmp, W_lin, out);
}